// Round 1
// baseline (783.253 us; speedup 1.0000x reference)
//
#include <hip/hip_runtime.h>
#include <math.h>

#define NNODES 50000
#define NEDGES 800000
#define FIN    1433
#define KP1    1472   // FIN padded to multiple of 64
#define HDIM   256
#define NCLS   7
#define MPAD   50048  // NNODES padded to multiple of 64

typedef __attribute__((ext_vector_type(8))) short short8;
typedef __attribute__((ext_vector_type(4))) float f32x4;

__device__ __forceinline__ unsigned short f2bf(float f) {
    unsigned u = __builtin_bit_cast(unsigned, f);
    u += 0x7fffu + ((u >> 16) & 1u);          // round-to-nearest-even
    return (unsigned short)(u >> 16);
}

__device__ __forceinline__ float bf2f(unsigned short u) {
    unsigned v = ((unsigned)u) << 16;
    return __builtin_bit_cast(float, v);
}

__device__ __forceinline__ void gl2lds16(const void* g, void* l) {
    __builtin_amdgcn_global_load_lds(
        (const __attribute__((address_space(1))) unsigned int*)g,
        (__attribute__((address_space(3))) unsigned int*)l, 16, 0, 0);
}

// ---------------- CSR construction ----------------

__global__ void count_kernel(const int* __restrict__ col, int* __restrict__ cnt, int E) {
    int e = blockIdx.x * blockDim.x + threadIdx.x;
    if (e < E) atomicAdd(&cnt[col[e]], 1);
}

__global__ __launch_bounds__(1024) void scan_kernel(const int* __restrict__ cnt,
                                                    int* __restrict__ rp,
                                                    float* __restrict__ dinv,
                                                    int n, int total) {
    __shared__ int sums[1024];
    int t = threadIdx.x;
    int chunk = (n + 1023) >> 10;
    int start = t * chunk;
    int end = start + chunk; if (end > n) end = n;
    int local = 0;
    for (int j = start; j < end; ++j) local += cnt[j];
    sums[t] = local;
    __syncthreads();
    for (int off = 1; off < 1024; off <<= 1) {
        int v = (t >= off) ? sums[t - off] : 0;
        __syncthreads();
        sums[t] += v;
        __syncthreads();
    }
    int run = (t == 0) ? 0 : sums[t - 1];
    for (int j = start; j < end; ++j) {
        int c = cnt[j];
        rp[j] = run; run += c;
        dinv[j] = rsqrtf((float)(c + 1));
    }
    if (t == 0) rp[n] = total;
}

// fill + per-edge weight precompute (dinv ready: scan runs before fill)
__global__ void fill_kernel(const int* __restrict__ row, const int* __restrict__ col,
                            const int* __restrict__ rp, int* __restrict__ cur,
                            int* __restrict__ csr, float* __restrict__ wcsr,
                            const float* __restrict__ dinv, int E) {
    int e = blockIdx.x * blockDim.x + threadIdx.x;
    if (e < E) {
        int c = col[e], r = row[e];
        int pos = rp[c] + atomicAdd(&cur[c], 1);
        csr[pos] = r;
        wcsr[pos] = dinv[r] * dinv[c];
    }
}

// ---------------- weight transpose+cast: Wt[Nn][Kp] <- W[Kin][Nn] ----------------

__global__ void cast_wt_kernel(const float* __restrict__ W, unsigned short* __restrict__ Wt,
                               int Kin, int Kp, int Nn) {
    int idx = blockIdx.x * blockDim.x + threadIdx.x;
    if (idx >= Nn * Kp) return;
    int n = idx / Kp, k = idx % Kp;
    float f = (k < Kin) ? W[(size_t)k * Nn + n] : 0.f;
    Wt[idx] = f2bf(f);
}

// ---------------- layer-1 GEMM: fused cast, coalesced staging, X-prefetch pipeline ------
// C[NNODES,256] bf16 = X[N,FIN] f32 @ W1t[256,KP1]^T bf16. BM=64, BN=256, BK=64.
// A: per instr one wave reads 64 consecutive f32 of one row (coalesced 256 B), cvt in regs,
// ds_write_b16 into XOR-swizzled chunk layout (2 lanes/bank = free).
// B: global_load_lds width-16; swizzle folded into per-lane GLOBAL address (LDS side linear).
// Pipeline (T14 async-stage split): X loads for chunk t+1 issue right after the first
// barrier of chunk t, so the 32-MFMA block covers their HBM latency; consumed next iter.

__global__ __launch_bounds__(256) void gemm1_fused(const float* __restrict__ X,
                                                   const unsigned short* __restrict__ Bt,
                                                   unsigned short* __restrict__ C) {
    __shared__ __align__(16) unsigned short As[64 * 64];    // 8 KB
    __shared__ __align__(16) unsigned short Bs[256 * 64];   // 32 KB
    const int tid = threadIdx.x;
    const int wave = tid >> 6, lane = tid & 63;
    const int m0 = blockIdx.x * 64;
    const int wn = wave * 64;
    const int kq = lane >> 4, l16 = lane & 15, l8 = lane & 7, lh = lane >> 3;

    int rowbase[16];
    #pragma unroll
    for (int i = 0; i < 16; ++i) {
        int r = m0 + i * 4 + wave;             // wave w stages rows {i*4+w}
        if (r >= NNODES) r = NNODES - 1;       // clamp: stay in-bounds, filtered at store
        rowbase[i] = r * FIN;
    }
    // LDS write index: row = i*4+wave -> row&7 = wave + 4*(i&1)
    const int aw0 = wave * 64 + ((lh ^ wave) * 8) + l8;
    const int aw1 = wave * 64 + ((lh ^ (wave + 4)) * 8) + l8;

    int bo[8];
    #pragma unroll
    for (int i = 0; i < 8; ++i) {
        int c = i * 256 + tid;                 // LDS chunk = linear c
        int n = c >> 3, ccg = (c & 7) ^ (n & 7);
        bo[i] = n * KP1 + ccg * 8;             // permuted global chunk
    }

    // fragment offsets: m = i*16+l16 -> m&7 = l16&7 (i*16 ≡ 0 mod 8); same for n
    int aoffb[2], boffb[2];
    #pragma unroll
    for (int ks = 0; ks < 2; ++ks) {
        int swz = ((ks * 4 + kq) ^ (l16 & 7)) * 8;
        aoffb[ks] = l16 * 64 + swz;
        boffb[ks] = (wn + l16) * 64 + swz;
    }

    f32x4 acc[4][4] = {};
    constexpr int NT = KP1 / 64;               // 23 k-chunks; only the last crosses FIN

    float fv[16];
    {   // prologue: chunk 0 (k = lane < 64 << FIN, no tail mask needed)
        #pragma unroll
        for (int i = 0; i < 16; ++i) fv[i] = X[rowbase[i] + lane];
    }

    for (int t = 0; t < NT; ++t) {
        const int k0 = t * 64;
        #pragma unroll
        for (int i = 0; i < 8; ++i)
            gl2lds16(Bt + bo[i] + k0, &Bs[(i * 256 + tid) * 8]);
        #pragma unroll
        for (int i = 0; i < 16; ++i)
            As[i * 256 + ((i & 1) ? aw1 : aw0)] = f2bf(fv[i]);
        __syncthreads();

        // prefetch chunk t+1 while the MFMAs below run (uniform branch)
        float nv[16];
        const bool more = (t + 1 < NT);
        if (more) {
            const int k = k0 + 64 + lane;
            const bool tail = (t + 2 == NT);   // last chunk: k may reach 1471 >= FIN
            #pragma unroll
            for (int i = 0; i < 16; ++i)
                nv[i] = (!tail || k < FIN) ? X[rowbase[i] + k] : 0.f;
        }

        #pragma unroll
        for (int ks = 0; ks < 2; ++ks) {
            short8 af[4], bg[4];
            #pragma unroll
            for (int i = 0; i < 4; ++i) af[i] = *(const short8*)&As[i * 1024 + aoffb[ks]];
            #pragma unroll
            for (int j = 0; j < 4; ++j) bg[j] = *(const short8*)&Bs[j * 1024 + boffb[ks]];
            #pragma unroll
            for (int i = 0; i < 4; ++i)
                #pragma unroll
                for (int j = 0; j < 4; ++j)
                    acc[i][j] = __builtin_amdgcn_mfma_f32_16x16x32_bf16(af[i], bg[j], acc[i][j], 0, 0, 0);
        }
        __syncthreads();
        if (more) {
            #pragma unroll
            for (int i = 0; i < 16; ++i) fv[i] = nv[i];
        }
    }

    // C/D layout: col = lane&15, row = (lane>>4)*4 + reg
    #pragma unroll
    for (int i = 0; i < 4; ++i) {
        int gm_base = m0 + i * 16 + (lane >> 4) * 4;
        #pragma unroll
        for (int r = 0; r < 4; ++r) {
            int gm = gm_base + r;
            if (gm < NNODES) {
                #pragma unroll
                for (int j = 0; j < 4; ++j) {
                    int gn = wn + j * 16 + l16;
                    C[(size_t)gm * HDIM + gn] = f2bf(acc[i][j][r]);
                }
            }
        }
    }
}

// ---------------- layer-2 GEMM: bf16 A, all global_load_lds, BM=64 BN=256 BK=64 ----------

__global__ __launch_bounds__(256) void gemm2_lds(const unsigned short* __restrict__ A,
                                                 const unsigned short* __restrict__ Bt,
                                                 unsigned short* __restrict__ C) {
    __shared__ __align__(16) unsigned short As[64 * 64];
    __shared__ __align__(16) unsigned short Bs[256 * 64];
    const int tid = threadIdx.x;
    const int wave = tid >> 6, lane = tid & 63;
    const int m0 = blockIdx.x * 64;
    const int wn = wave * 64;
    const int kq = lane >> 4, l16 = lane & 15;

    int ao[2];
    #pragma unroll
    for (int i = 0; i < 2; ++i) {
        int c = i * 256 + tid;
        int m = c >> 3, ccg = (c & 7) ^ (m & 7);
        ao[i] = (m0 + m) * HDIM + ccg * 8;     // pad rows: finite poison, discarded at store
    }
    int bo[8];
    #pragma unroll
    for (int i = 0; i < 8; ++i) {
        int c = i * 256 + tid;
        int n = c >> 3, ccg = (c & 7) ^ (n & 7);
        bo[i] = n * HDIM + ccg * 8;
    }
    int aoffb[2], boffb[2];
    #pragma unroll
    for (int ks = 0; ks < 2; ++ks) {
        int swz = ((ks * 4 + kq) ^ (l16 & 7)) * 8;
        aoffb[ks] = l16 * 64 + swz;
        boffb[ks] = (wn + l16) * 64 + swz;
    }

    f32x4 acc[4][4] = {};
    #pragma unroll
    for (int k0 = 0; k0 < HDIM; k0 += 64) {
        #pragma unroll
        for (int i = 0; i < 2; ++i) gl2lds16(A + ao[i] + k0, &As[(i * 256 + tid) * 8]);
        #pragma unroll
        for (int i = 0; i < 8; ++i) gl2lds16(Bt + bo[i] + k0, &Bs[(i * 256 + tid) * 8]);
        __syncthreads();
        #pragma unroll
        for (int ks = 0; ks < 2; ++ks) {
            short8 af[4], bg[4];
            #pragma unroll
            for (int i = 0; i < 4; ++i) af[i] = *(const short8*)&As[i * 1024 + aoffb[ks]];
            #pragma unroll
            for (int j = 0; j < 4; ++j) bg[j] = *(const short8*)&Bs[j * 1024 + boffb[ks]];
            #pragma unroll
            for (int i = 0; i < 4; ++i)
                #pragma unroll
                for (int j = 0; j < 4; ++j)
                    acc[i][j] = __builtin_amdgcn_mfma_f32_16x16x32_bf16(af[i], bg[j], acc[i][j], 0, 0, 0);
        }
        __syncthreads();
    }

    #pragma unroll
    for (int i = 0; i < 4; ++i) {
        int gm_base = m0 + i * 16 + (lane >> 4) * 4;
        #pragma unroll
        for (int r = 0; r < 4; ++r) {
            int gm = gm_base + r;
            if (gm < NNODES) {
                #pragma unroll
                for (int j = 0; j < 4; ++j) {
                    int gn = wn + j * 16 + l16;
                    C[(size_t)gm * HDIM + gn] = f2bf(acc[i][j][r]);
                }
            }
        }
    }
}

// ---------------- shared aggregation inner loop (unroll-8: index loads batch-issue,
// then gathers batch-issue -> one serial latency round per 8 edges instead of per 4) -----

__device__ __forceinline__ void aggregate_row(const ushort4* __restrict__ h, int lane,
                                              int p, int p1,
                                              const int* __restrict__ csr,
                                              const float* __restrict__ wcsr,
                                              float& ax, float& ay, float& az, float& aw) {
    for (; p + 8 <= p1; p += 8) {
        int s[8]; float wv[8];
        #pragma unroll
        for (int j = 0; j < 8; ++j) { s[j] = csr[p + j]; wv[j] = wcsr[p + j]; }
        ushort4 t[8];
        #pragma unroll
        for (int j = 0; j < 8; ++j) t[j] = h[s[j] * 64 + lane];
        #pragma unroll
        for (int j = 0; j < 8; ++j) {
            ax += wv[j] * bf2f(t[j].x); ay += wv[j] * bf2f(t[j].y);
            az += wv[j] * bf2f(t[j].z); aw += wv[j] * bf2f(t[j].w);
        }
    }
    if (p + 4 <= p1) {
        int s[4]; float wv[4];
        #pragma unroll
        for (int j = 0; j < 4; ++j) { s[j] = csr[p + j]; wv[j] = wcsr[p + j]; }
        ushort4 t[4];
        #pragma unroll
        for (int j = 0; j < 4; ++j) t[j] = h[s[j] * 64 + lane];
        #pragma unroll
        for (int j = 0; j < 4; ++j) {
            ax += wv[j] * bf2f(t[j].x); ay += wv[j] * bf2f(t[j].y);
            az += wv[j] * bf2f(t[j].z); aw += wv[j] * bf2f(t[j].w);
        }
        p += 4;
    }
    for (; p < p1; ++p) {
        int s = csr[p];
        float wg = wcsr[p];
        ushort4 t = h[s * 64 + lane];
        ax += wg * bf2f(t.x); ay += wg * bf2f(t.y); az += wg * bf2f(t.z); aw += wg * bf2f(t.w);
    }
}

// ---------------- aggregation layer 1 (bf16 in/out, precomputed weights) ---------

__global__ __launch_bounds__(256) void agg_kernel(const ushort4* __restrict__ h,
                                                  ushort4* __restrict__ out,
                                                  const float* __restrict__ dinv,
                                                  const int* __restrict__ rp,
                                                  const int* __restrict__ csr,
                                                  const float* __restrict__ wcsr,
                                                  const float* __restrict__ bias,
                                                  int n) {
    int node = blockIdx.x * 4 + (threadIdx.x >> 6);
    int lane = threadIdx.x & 63;
    if (node >= n) return;
    float di = dinv[node];
    float sw = di * di;
    ushort4 hv = h[node * 64 + lane];
    float ax = sw * bf2f(hv.x), ay = sw * bf2f(hv.y);
    float az = sw * bf2f(hv.z), aw = sw * bf2f(hv.w);
    aggregate_row(h, lane, rp[node], rp[node + 1], csr, wcsr, ax, ay, az, aw);
    float4 b = ((const float4*)bias)[lane];
    ax = fmaxf(ax + b.x, 0.f); ay = fmaxf(ay + b.y, 0.f);
    az = fmaxf(az + b.z, 0.f); aw = fmaxf(aw + b.w, 0.f);
    out[node * 64 + lane] = make_ushort4(f2bf(ax), f2bf(ay), f2bf(az), f2bf(aw));
}

// ---------------- aggregation layer 2 fused with mm3: h3[N,7] ----------------

__global__ __launch_bounds__(256) void agg2_mm3_kernel(const ushort4* __restrict__ h,
                                                       float* __restrict__ h3,
                                                       const float* __restrict__ dinv,
                                                       const int* __restrict__ rp,
                                                       const int* __restrict__ csr,
                                                       const float* __restrict__ wcsr,
                                                       const float* __restrict__ bias,
                                                       const float* __restrict__ W3,
                                                       int n) {
    __shared__ __align__(16) float Ws[NCLS * HDIM];   // Ws[c*256 + k] = W3[k*7 + c]
    int tid = threadIdx.x;
    for (int i = tid; i < NCLS * HDIM; i += 256)
        Ws[i] = W3[(i & 255) * NCLS + (i >> 8)];
    __syncthreads();

    int node = blockIdx.x * 4 + (tid >> 6);
    int lane = tid & 63;
    if (node >= n) return;
    float di = dinv[node];
    float sw = di * di;
    ushort4 hv = h[node * 64 + lane];
    float ax = sw * bf2f(hv.x), ay = sw * bf2f(hv.y);
    float az = sw * bf2f(hv.z), aw = sw * bf2f(hv.w);
    aggregate_row(h, lane, rp[node], rp[node + 1], csr, wcsr, ax, ay, az, aw);
    float4 b = ((const float4*)bias)[lane];
    ax = fmaxf(ax + b.x, 0.f); ay = fmaxf(ay + b.y, 0.f);
    az = fmaxf(az + b.z, 0.f); aw = fmaxf(aw + b.w, 0.f);

    float p7[NCLS];
    #pragma unroll
    for (int c = 0; c < NCLS; ++c) {
        float4 w4 = *(const float4*)&Ws[c * HDIM + 4 * lane];
        p7[c] = ax * w4.x + ay * w4.y + az * w4.z + aw * w4.w;
    }
    #pragma unroll
    for (int c = 0; c < NCLS; ++c)
        for (int off = 32; off > 0; off >>= 1) p7[c] += __shfl_down(p7[c], off);
    if (lane == 0) {
        #pragma unroll
        for (int c = 0; c < NCLS; ++c) h3[node * NCLS + c] = p7[c];
    }
}

// ---------------- layer-3 aggregation + bias + log_softmax ----------------

__global__ void final_kernel(const float* __restrict__ h3, const float* __restrict__ dinv,
                             const int* __restrict__ rp, const int* __restrict__ csr,
                             const float* __restrict__ wcsr,
                             const float* __restrict__ b3, float* __restrict__ out, int n) {
    int i = blockIdx.x * blockDim.x + threadIdx.x;
    if (i >= n) return;
    float di = dinv[i];
    float sw = di * di;
    float acc[NCLS];
    #pragma unroll
    for (int c = 0; c < NCLS; ++c) acc[c] = sw * h3[i * NCLS + c];
    int p = rp[i], p1 = rp[i + 1];
    for (; p + 4 <= p1; p += 4) {
        int s0 = csr[p], s1 = csr[p + 1], s2 = csr[p + 2], s3 = csr[p + 3];
        float w0 = wcsr[p], w1 = wcsr[p + 1], w2 = wcsr[p + 2], w3 = wcsr[p + 3];
        #pragma unroll
        for (int c = 0; c < NCLS; ++c)
            acc[c] += w0 * h3[s0 * NCLS + c] + w1 * h3[s1 * NCLS + c]
                    + w2 * h3[s2 * NCLS + c] + w3 * h3[s3 * NCLS + c];
    }
    for (; p < p1; ++p) {
        int s = csr[p];
        float wg = wcsr[p];
        #pragma unroll
        for (int c = 0; c < NCLS; ++c) acc[c] += wg * h3[s * NCLS + c];
    }
    float mx = -1e30f;
    #pragma unroll
    for (int c = 0; c < NCLS; ++c) { acc[c] += b3[c]; mx = fmaxf(mx, acc[c]); }
    float sum = 0.f;
    #pragma unroll
    for (int c = 0; c < NCLS; ++c) sum += expf(acc[c] - mx);
    float lse = mx + logf(sum);
    #pragma unroll
    for (int c = 0; c < NCLS; ++c) out[i * NCLS + c] = acc[c] - lse;
}

// ---------------- launch ----------------

extern "C" void kernel_launch(void* const* d_in, const int* in_sizes, int n_in,
                              void* d_out, int out_size, void* d_ws, size_t ws_size,
                              hipStream_t stream) {
    const float* x  = (const float*)d_in[0];
    const int*   ei = (const int*)d_in[1];
    const float* W1 = (const float*)d_in[2];
    const float* b1 = (const float*)d_in[3];
    const float* W2 = (const float*)d_in[4];
    const float* b2 = (const float*)d_in[5];
    const float* W3 = (const float*)d_in[6];
    const float* b3 = (const float*)d_in[7];
    float* out = (float*)d_out;
    const int* row = ei;
    const int* col = ei + NEDGES;

    char* w = (char*)d_ws;
    auto alloc = [&](size_t b) { void* p = (void*)w; w += (b + 255) & ~(size_t)255; return p; };
    int*   cnt  = (int*)alloc(NNODES * 4);
    int*   cur  = (int*)alloc(NNODES * 4);
    int*   rp   = (int*)alloc((NNODES + 1) * 4);
    float* dinv = (float*)alloc(NNODES * 4);
    int*   csr  = (int*)alloc((size_t)NEDGES * 4);
    float* wcsr = (float*)alloc((size_t)NEDGES * 4);
    unsigned short* w1t  = (unsigned short*)alloc((size_t)HDIM * KP1 * 2);
    unsigned short* w2t  = (unsigned short*)alloc((size_t)HDIM * HDIM * 2);
    unsigned short* h_bf = (unsigned short*)alloc((size_t)MPAD * HDIM * 2);
    unsigned short* a_bf = (unsigned short*)alloc((size_t)MPAD * HDIM * 2);
    float* h3 = (float*)alloc((size_t)NNODES * NCLS * 4);

    hipMemsetAsync(cnt, 0, NNODES * 4, stream);
    hipMemsetAsync(cur, 0, NNODES * 4, stream);
    count_kernel<<<(NEDGES + 255) / 256, 256, 0, stream>>>(col, cnt, NEDGES);
    scan_kernel<<<1, 1024, 0, stream>>>(cnt, rp, dinv, NNODES, NEDGES);
    fill_kernel<<<(NEDGES + 255) / 256, 256, 0, stream>>>(row, col, rp, cur, csr, wcsr, dinv, NEDGES);

    cast_wt_kernel<<<(HDIM * KP1 + 255) / 256, 256, 0, stream>>>(W1, w1t, FIN, KP1, HDIM);
    cast_wt_kernel<<<(HDIM * HDIM + 255) / 256, 256, 0, stream>>>(W2, w2t, HDIM, HDIM, HDIM);

    gemm1_fused<<<MPAD / 64, 256, 0, stream>>>(x, w1t, h_bf);
    agg_kernel<<<(NNODES + 3) / 4, 256, 0, stream>>>((const ushort4*)h_bf, (ushort4*)a_bf,
                                                     dinv, rp, csr, wcsr, b1, NNODES);
    gemm2_lds<<<MPAD / 64, 256, 0, stream>>>(a_bf, w2t, h_bf);
    agg2_mm3_kernel<<<(NNODES + 3) / 4, 256, 0, stream>>>((const ushort4*)h_bf, h3,
                                                          dinv, rp, csr, wcsr, b2, W3, NNODES);
    final_kernel<<<(NNODES + 255) / 256, 256, 0, stream>>>(h3, dinv, rp, csr, wcsr, b3, out, NNODES);
}

// Round 2
// 676.827 us; speedup vs baseline: 1.1572x; 1.1572x over previous
//
#include <hip/hip_runtime.h>
#include <math.h>

#define NNODES 50000
#define NEDGES 800000
#define FIN    1433
#define KP1    1472   // FIN padded to multiple of 64
#define HDIM   256
#define NCLS   7
#define MPAD   50048  // NNODES padded to multiple of 64

typedef __attribute__((ext_vector_type(8))) short short8;
typedef __attribute__((ext_vector_type(4))) float f32x4;

__device__ __forceinline__ unsigned short f2bf(float f) {
    unsigned u = __builtin_bit_cast(unsigned, f);
    u += 0x7fffu + ((u >> 16) & 1u);          // round-to-nearest-even
    return (unsigned short)(u >> 16);
}

__device__ __forceinline__ float bf2f(unsigned short u) {
    unsigned v = ((unsigned)u) << 16;
    return __builtin_bit_cast(float, v);
}

__device__ __forceinline__ void gl2lds16(const void* g, void* l) {
    __builtin_amdgcn_global_load_lds(
        (const __attribute__((address_space(1))) unsigned int*)g,
        (__attribute__((address_space(3))) unsigned int*)l, 16, 0, 0);
}

// unaligned-safe 16 B load (X rows are only 4 B aligned: FIN=1433)
__device__ __forceinline__ f32x4 ld4u(const float* p) {
    f32x4 v; __builtin_memcpy(&v, p, 16); return v;
}

// ---------------- CSR construction ----------------

__global__ void count_kernel(const int* __restrict__ col, int* __restrict__ cnt, int E) {
    int e = blockIdx.x * blockDim.x + threadIdx.x;
    if (e < E) atomicAdd(&cnt[col[e]], 1);
}

// 3-stage parallel scan (replaces the single-block serializer)
#define SCAN_BS 512

__global__ __launch_bounds__(SCAN_BS) void scan_part(const int* __restrict__ cnt,
                                                     int* __restrict__ bsum, int n) {
    __shared__ int red[SCAN_BS];
    int t = threadIdx.x;
    int i = blockIdx.x * SCAN_BS + t;
    red[t] = (i < n) ? cnt[i] : 0;
    __syncthreads();
    for (int off = SCAN_BS / 2; off > 0; off >>= 1) {
        if (t < off) red[t] += red[t + off];
        __syncthreads();
    }
    if (t == 0) bsum[blockIdx.x] = red[0];
}

__global__ __launch_bounds__(128) void scan_top(int* __restrict__ bsum, int nb) {
    __shared__ int s[128];
    int t = threadIdx.x;
    int v = (t < nb) ? bsum[t] : 0;
    s[t] = v;
    __syncthreads();
    for (int off = 1; off < 128; off <<= 1) {
        int u = (t >= off) ? s[t - off] : 0;
        __syncthreads();
        s[t] += u;
        __syncthreads();
    }
    if (t < nb) bsum[t] = s[t] - v;            // exclusive
}

__global__ __launch_bounds__(SCAN_BS) void scan_apply(const int* __restrict__ cnt,
                                                      const int* __restrict__ bsum,
                                                      int* __restrict__ rp,
                                                      float* __restrict__ dinv,
                                                      int n, int total) {
    __shared__ int s[SCAN_BS];
    int t = threadIdx.x;
    int i = blockIdx.x * SCAN_BS + t;
    int v = (i < n) ? cnt[i] : 0;
    s[t] = v;
    __syncthreads();
    for (int off = 1; off < SCAN_BS; off <<= 1) {
        int u = (t >= off) ? s[t - off] : 0;
        __syncthreads();
        s[t] += u;
        __syncthreads();
    }
    if (i < n) {
        rp[i] = bsum[blockIdx.x] + s[t] - v;   // exclusive prefix
        dinv[i] = rsqrtf((float)(v + 1));
    }
    if (i == n) rp[n] = total;
}

// fill + per-edge weight precompute, packed {src, weight} per edge (one 8 B store)
__global__ void fill_kernel(const int* __restrict__ row, const int* __restrict__ col,
                            const int* __restrict__ rp, int* __restrict__ cur,
                            int2* __restrict__ csrw,
                            const float* __restrict__ dinv, int E) {
    int e = blockIdx.x * blockDim.x + threadIdx.x;
    if (e < E) {
        int c = col[e], r = row[e];
        int pos = rp[c] + atomicAdd(&cur[c], 1);
        csrw[pos] = make_int2(r, __float_as_int(dinv[r] * dinv[c]));
    }
}

// ---------------- weight transpose+cast (both weights in one launch) ----------------

__global__ void cast_wt2(const float* __restrict__ W1, const float* __restrict__ W2,
                         unsigned short* __restrict__ w1t, unsigned short* __restrict__ w2t) {
    int idx = blockIdx.x * blockDim.x + threadIdx.x;
    if (idx < HDIM * KP1) {
        int n = idx / KP1, k = idx % KP1;
        w1t[idx] = f2bf((k < FIN) ? W1[(size_t)k * HDIM + n] : 0.f);
    } else {
        int j = idx - HDIM * KP1;
        if (j < HDIM * HDIM) {
            int n = j / HDIM, k = j % HDIM;
            w2t[j] = f2bf(W2[(size_t)k * HDIM + n]);
        }
    }
}

// ---------------- layer-1 GEMM: fused cast, vectorized staging, X-prefetch pipeline -----
// C[NNODES,256] bf16 = X[N,FIN] f32 @ W1t[256,KP1]^T bf16. BM=64, BN=256, BK=64.
// A: wave w owns rows [w*16, w*16+16). Per instr: lane (lq=lane>>4, h=lane&15) loads the
//    16 B k-quad h of row base+lq (4 rows per instr, 4 instrs per k-chunk instead of 16
//    scalar loads). Store: pack 4 bf16 -> one ds_write_b64 into the XOR-swizzled layout.
// B: global_load_lds width-16; swizzle folded into per-lane GLOBAL address (LDS linear).
// Pipeline: X loads for chunk t+1 issue after the first barrier of chunk t (MFMAs cover
// their latency); consumed next iteration.

__global__ __launch_bounds__(256) void gemm1_fused(const float* __restrict__ X,
                                                   const unsigned short* __restrict__ Bt,
                                                   unsigned short* __restrict__ C) {
    __shared__ __align__(16) unsigned short As[64 * 64];    // 8 KB
    __shared__ __align__(16) unsigned short Bs[256 * 64];   // 32 KB
    const int tid = threadIdx.x;
    const int wave = tid >> 6, lane = tid & 63;
    const int m0 = blockIdx.x * 64;
    const int wn = wave * 64;
    const int kq = lane >> 4, l16 = lane & 15;
    const int lq = lane >> 4;      // row within 4-row group
    const int h  = lane & 15;      // k-quad (half-chunk) index, 16 per row

    int rowbase[4];
    #pragma unroll
    for (int i = 0; i < 4; ++i) {
        int r = m0 + wave * 16 + i * 4 + lq;
        if (r >= NNODES) r = NNODES - 1;       // clamp: in-bounds, filtered at store
        rowbase[i] = r * FIN;
    }
    // LDS write offsets: row r = wave*16 + i*4 + lq -> r&7 = lq + 4*(i&1)
    int aw[4];
    #pragma unroll
    for (int i = 0; i < 4; ++i) {
        int r7 = lq + 4 * (i & 1);
        aw[i] = (wave * 16 + i * 4 + lq) * 64 + (((h >> 1) ^ r7) * 8) + (h & 1) * 4;
    }

    int bo[8];
    #pragma unroll
    for (int i = 0; i < 8; ++i) {
        int c = i * 256 + tid;                 // LDS chunk = linear c
        int n = c >> 3, ccg = (c & 7) ^ (n & 7);
        bo[i] = n * KP1 + ccg * 8;             // permuted global chunk
    }

    int aoffb[2], boffb[2];
    #pragma unroll
    for (int ks = 0; ks < 2; ++ks) {
        int swz = ((ks * 4 + kq) ^ (l16 & 7)) * 8;
        aoffb[ks] = l16 * 64 + swz;
        boffb[ks] = (wn + l16) * 64 + swz;
    }

    f32x4 acc[4][4] = {};
    constexpr int NT = KP1 / 64;               // 23 k-chunks; only the last crosses FIN

    f32x4 fv[4];
    #pragma unroll
    for (int i = 0; i < 4; ++i) fv[i] = ld4u(&X[rowbase[i] + h * 4]);   // chunk 0, k<64<FIN

    for (int t = 0; t < NT; ++t) {
        const int k0 = t * 64;
        #pragma unroll
        for (int i = 0; i < 8; ++i)
            gl2lds16(Bt + bo[i] + k0, &Bs[(i * 256 + tid) * 8]);
        #pragma unroll
        for (int i = 0; i < 4; ++i) {
            ushort4 pk = make_ushort4(f2bf(fv[i].x), f2bf(fv[i].y),
                                      f2bf(fv[i].z), f2bf(fv[i].w));
            *(ushort4*)&As[aw[i]] = pk;
        }
        __syncthreads();

        // prefetch chunk t+1 while the MFMAs below run (uniform branch)
        f32x4 nv[4];
        const bool more = (t + 1 < NT);
        if (more) {
            const int kb = k0 + 64 + h * 4;
            if (t + 2 == NT) {                 // last chunk: kb may reach 1468 >= FIN
                #pragma unroll
                for (int i = 0; i < 4; ++i) {
                    float a = (kb + 0 < FIN) ? X[rowbase[i] + kb + 0] : 0.f;
                    float b = (kb + 1 < FIN) ? X[rowbase[i] + kb + 1] : 0.f;
                    float c = (kb + 2 < FIN) ? X[rowbase[i] + kb + 2] : 0.f;
                    float d = (kb + 3 < FIN) ? X[rowbase[i] + kb + 3] : 0.f;
                    nv[i] = (f32x4){a, b, c, d};
                }
            } else {
                #pragma unroll
                for (int i = 0; i < 4; ++i) nv[i] = ld4u(&X[rowbase[i] + kb]);
            }
        }

        #pragma unroll
        for (int ks = 0; ks < 2; ++ks) {
            short8 af[4], bg[4];
            #pragma unroll
            for (int i = 0; i < 4; ++i) af[i] = *(const short8*)&As[i * 1024 + aoffb[ks]];
            #pragma unroll
            for (int j = 0; j < 4; ++j) bg[j] = *(const short8*)&Bs[j * 1024 + boffb[ks]];
            #pragma unroll
            for (int i = 0; i < 4; ++i)
                #pragma unroll
                for (int j = 0; j < 4; ++j)
                    acc[i][j] = __builtin_amdgcn_mfma_f32_16x16x32_bf16(af[i], bg[j], acc[i][j], 0, 0, 0);
        }
        __syncthreads();
        if (more) {
            #pragma unroll
            for (int i = 0; i < 4; ++i) fv[i] = nv[i];
        }
    }

    // C/D layout: col = lane&15, row = (lane>>4)*4 + reg
    #pragma unroll
    for (int i = 0; i < 4; ++i) {
        int gm_base = m0 + i * 16 + (lane >> 4) * 4;
        #pragma unroll
        for (int r = 0; r < 4; ++r) {
            int gm = gm_base + r;
            if (gm < NNODES) {
                #pragma unroll
                for (int j = 0; j < 4; ++j) {
                    int gn = wn + j * 16 + l16;
                    C[(size_t)gm * HDIM + gn] = f2bf(acc[i][j][r]);
                }
            }
        }
    }
}

// ---------------- layer-2 GEMM: bf16 A, all global_load_lds, BM=64 BN=256 BK=64 ----------

__global__ __launch_bounds__(256) void gemm2_lds(const unsigned short* __restrict__ A,
                                                 const unsigned short* __restrict__ Bt,
                                                 unsigned short* __restrict__ C) {
    __shared__ __align__(16) unsigned short As[64 * 64];
    __shared__ __align__(16) unsigned short Bs[256 * 64];
    const int tid = threadIdx.x;
    const int wave = tid >> 6, lane = tid & 63;
    const int m0 = blockIdx.x * 64;
    const int wn = wave * 64;
    const int kq = lane >> 4, l16 = lane & 15;

    int ao[2];
    #pragma unroll
    for (int i = 0; i < 2; ++i) {
        int c = i * 256 + tid;
        int m = c >> 3, ccg = (c & 7) ^ (m & 7);
        ao[i] = (m0 + m) * HDIM + ccg * 8;     // pad rows: finite poison, discarded at store
    }
    int bo[8];
    #pragma unroll
    for (int i = 0; i < 8; ++i) {
        int c = i * 256 + tid;
        int n = c >> 3, ccg = (c & 7) ^ (n & 7);
        bo[i] = n * HDIM + ccg * 8;
    }
    int aoffb[2], boffb[2];
    #pragma unroll
    for (int ks = 0; ks < 2; ++ks) {
        int swz = ((ks * 4 + kq) ^ (l16 & 7)) * 8;
        aoffb[ks] = l16 * 64 + swz;
        boffb[ks] = (wn + l16) * 64 + swz;
    }

    f32x4 acc[4][4] = {};
    #pragma unroll
    for (int k0 = 0; k0 < HDIM; k0 += 64) {
        #pragma unroll
        for (int i = 0; i < 2; ++i) gl2lds16(A + ao[i] + k0, &As[(i * 256 + tid) * 8]);
        #pragma unroll
        for (int i = 0; i < 8; ++i) gl2lds16(Bt + bo[i] + k0, &Bs[(i * 256 + tid) * 8]);
        __syncthreads();
        #pragma unroll
        for (int ks = 0; ks < 2; ++ks) {
            short8 af[4], bg[4];
            #pragma unroll
            for (int i = 0; i < 4; ++i) af[i] = *(const short8*)&As[i * 1024 + aoffb[ks]];
            #pragma unroll
            for (int j = 0; j < 4; ++j) bg[j] = *(const short8*)&Bs[j * 1024 + boffb[ks]];
            #pragma unroll
            for (int i = 0; i < 4; ++i)
                #pragma unroll
                for (int j = 0; j < 4; ++j)
                    acc[i][j] = __builtin_amdgcn_mfma_f32_16x16x32_bf16(af[i], bg[j], acc[i][j], 0, 0, 0);
        }
        __syncthreads();
    }

    #pragma unroll
    for (int i = 0; i < 4; ++i) {
        int gm_base = m0 + i * 16 + (lane >> 4) * 4;
        #pragma unroll
        for (int r = 0; r < 4; ++r) {
            int gm = gm_base + r;
            if (gm < NNODES) {
                #pragma unroll
                for (int j = 0; j < 4; ++j) {
                    int gn = wn + j * 16 + l16;
                    C[(size_t)gm * HDIM + gn] = f2bf(acc[i][j][r]);
                }
            }
        }
    }
}

// ---------------- shared aggregation inner loop (packed int2 CSR, unroll-8) -----

__device__ __forceinline__ void aggregate_row(const ushort4* __restrict__ h, int lane,
                                              int p, int p1,
                                              const int2* __restrict__ csrw,
                                              float& ax, float& ay, float& az, float& aw) {
    for (; p + 8 <= p1; p += 8) {
        int2 e[8];
        #pragma unroll
        for (int j = 0; j < 8; ++j) e[j] = csrw[p + j];
        ushort4 t[8];
        #pragma unroll
        for (int j = 0; j < 8; ++j) t[j] = h[e[j].x * 64 + lane];
        #pragma unroll
        for (int j = 0; j < 8; ++j) {
            float w = __int_as_float(e[j].y);
            ax += w * bf2f(t[j].x); ay += w * bf2f(t[j].y);
            az += w * bf2f(t[j].z); aw += w * bf2f(t[j].w);
        }
    }
    if (p + 4 <= p1) {
        int2 e[4];
        #pragma unroll
        for (int j = 0; j < 4; ++j) e[j] = csrw[p + j];
        ushort4 t[4];
        #pragma unroll
        for (int j = 0; j < 4; ++j) t[j] = h[e[j].x * 64 + lane];
        #pragma unroll
        for (int j = 0; j < 4; ++j) {
            float w = __int_as_float(e[j].y);
            ax += w * bf2f(t[j].x); ay += w * bf2f(t[j].y);
            az += w * bf2f(t[j].z); aw += w * bf2f(t[j].w);
        }
        p += 4;
    }
    for (; p < p1; ++p) {
        int2 e = csrw[p];
        float w = __int_as_float(e.y);
        ushort4 t = h[e.x * 64 + lane];
        ax += w * bf2f(t.x); ay += w * bf2f(t.y); az += w * bf2f(t.z); aw += w * bf2f(t.w);
    }
}

// ---------------- aggregation layer 1 (bf16 in/out, precomputed weights) ---------

__global__ __launch_bounds__(256) void agg_kernel(const ushort4* __restrict__ h,
                                                  ushort4* __restrict__ out,
                                                  const float* __restrict__ dinv,
                                                  const int* __restrict__ rp,
                                                  const int2* __restrict__ csrw,
                                                  const float* __restrict__ bias,
                                                  int n) {
    int node = blockIdx.x * 4 + (threadIdx.x >> 6);
    int lane = threadIdx.x & 63;
    if (node >= n) return;
    float di = dinv[node];
    float sw = di * di;
    ushort4 hv = h[node * 64 + lane];
    float ax = sw * bf2f(hv.x), ay = sw * bf2f(hv.y);
    float az = sw * bf2f(hv.z), aw = sw * bf2f(hv.w);
    aggregate_row(h, lane, rp[node], rp[node + 1], csrw, ax, ay, az, aw);
    float4 b = ((const float4*)bias)[lane];
    ax = fmaxf(ax + b.x, 0.f); ay = fmaxf(ay + b.y, 0.f);
    az = fmaxf(az + b.z, 0.f); aw = fmaxf(aw + b.w, 0.f);
    out[node * 64 + lane] = make_ushort4(f2bf(ax), f2bf(ay), f2bf(az), f2bf(aw));
}

// ---------------- aggregation layer 2 fused with mm3: h3[N,7] ----------------

__global__ __launch_bounds__(256) void agg2_mm3_kernel(const ushort4* __restrict__ h,
                                                       float* __restrict__ h3,
                                                       const float* __restrict__ dinv,
                                                       const int* __restrict__ rp,
                                                       const int2* __restrict__ csrw,
                                                       const float* __restrict__ bias,
                                                       const float* __restrict__ W3,
                                                       int n) {
    __shared__ __align__(16) float Ws[NCLS * HDIM];   // Ws[c*256 + k] = W3[k*7 + c]
    int tid = threadIdx.x;
    for (int i = tid; i < NCLS * HDIM; i += 256)
        Ws[i] = W3[(i & 255) * NCLS + (i >> 8)];
    __syncthreads();

    int node = blockIdx.x * 4 + (tid >> 6);
    int lane = tid & 63;
    if (node >= n) return;
    float di = dinv[node];
    float sw = di * di;
    ushort4 hv = h[node * 64 + lane];
    float ax = sw * bf2f(hv.x), ay = sw * bf2f(hv.y);
    float az = sw * bf2f(hv.z), aw = sw * bf2f(hv.w);
    aggregate_row(h, lane, rp[node], rp[node + 1], csrw, ax, ay, az, aw);
    float4 b = ((const float4*)bias)[lane];
    ax = fmaxf(ax + b.x, 0.f); ay = fmaxf(ay + b.y, 0.f);
    az = fmaxf(az + b.z, 0.f); aw = fmaxf(aw + b.w, 0.f);

    float p7[NCLS];
    #pragma unroll
    for (int c = 0; c < NCLS; ++c) {
        float4 w4 = *(const float4*)&Ws[c * HDIM + 4 * lane];
        p7[c] = ax * w4.x + ay * w4.y + az * w4.z + aw * w4.w;
    }
    #pragma unroll
    for (int c = 0; c < NCLS; ++c)
        for (int off = 32; off > 0; off >>= 1) p7[c] += __shfl_down(p7[c], off);
    if (lane == 0) {
        #pragma unroll
        for (int c = 0; c < NCLS; ++c) h3[node * NCLS + c] = p7[c];
    }
}

// ---------------- layer-3 aggregation + bias + log_softmax ----------------

__global__ void final_kernel(const float* __restrict__ h3, const float* __restrict__ dinv,
                             const int* __restrict__ rp, const int2* __restrict__ csrw,
                             const float* __restrict__ b3, float* __restrict__ out, int n) {
    int i = blockIdx.x * blockDim.x + threadIdx.x;
    if (i >= n) return;
    float di = dinv[i];
    float sw = di * di;
    float acc[NCLS];
    #pragma unroll
    for (int c = 0; c < NCLS; ++c) acc[c] = sw * h3[i * NCLS + c];
    int p = rp[i], p1 = rp[i + 1];
    for (; p + 4 <= p1; p += 4) {
        int2 e0 = csrw[p], e1 = csrw[p + 1], e2 = csrw[p + 2], e3 = csrw[p + 3];
        float w0 = __int_as_float(e0.y), w1 = __int_as_float(e1.y);
        float w2 = __int_as_float(e2.y), w3 = __int_as_float(e3.y);
        #pragma unroll
        for (int c = 0; c < NCLS; ++c)
            acc[c] += w0 * h3[e0.x * NCLS + c] + w1 * h3[e1.x * NCLS + c]
                    + w2 * h3[e2.x * NCLS + c] + w3 * h3[e3.x * NCLS + c];
    }
    for (; p < p1; ++p) {
        int2 e = csrw[p];
        float wg = __int_as_float(e.y);
        #pragma unroll
        for (int c = 0; c < NCLS; ++c) acc[c] += wg * h3[e.x * NCLS + c];
    }
    float mx = -1e30f;
    #pragma unroll
    for (int c = 0; c < NCLS; ++c) { acc[c] += b3[c]; mx = fmaxf(mx, acc[c]); }
    float sum = 0.f;
    #pragma unroll
    for (int c = 0; c < NCLS; ++c) sum += expf(acc[c] - mx);
    float lse = mx + logf(sum);
    #pragma unroll
    for (int c = 0; c < NCLS; ++c) out[i * NCLS + c] = acc[c] - lse;
}

// ---------------- launch ----------------

extern "C" void kernel_launch(void* const* d_in, const int* in_sizes, int n_in,
                              void* d_out, int out_size, void* d_ws, size_t ws_size,
                              hipStream_t stream) {
    const float* x  = (const float*)d_in[0];
    const int*   ei = (const int*)d_in[1];
    const float* W1 = (const float*)d_in[2];
    const float* b1 = (const float*)d_in[3];
    const float* W2 = (const float*)d_in[4];
    const float* b2 = (const float*)d_in[5];
    const float* W3 = (const float*)d_in[6];
    const float* b3 = (const float*)d_in[7];
    float* out = (float*)d_out;
    const int* row = ei;
    const int* col = ei + NEDGES;

    char* w = (char*)d_ws;
    auto alloc = [&](size_t b) { void* p = (void*)w; w += (b + 255) & ~(size_t)255; return p; };
    int*   cnt  = (int*)alloc(NNODES * 4);
    int*   cur  = (int*)alloc(NNODES * 4);   // contiguous with cnt (both 256-padded)
    int*   rp   = (int*)alloc((NNODES + 1) * 4);
    float* dinv = (float*)alloc(NNODES * 4);
    int*   bsum = (int*)alloc(128 * 4);
    int2*  csrw = (int2*)alloc((size_t)NEDGES * 8);
    unsigned short* w1t  = (unsigned short*)alloc((size_t)HDIM * KP1 * 2);
    unsigned short* w2t  = (unsigned short*)alloc((size_t)HDIM * HDIM * 2);
    unsigned short* h_bf = (unsigned short*)alloc((size_t)MPAD * HDIM * 2);
    unsigned short* a_bf = (unsigned short*)alloc((size_t)MPAD * HDIM * 2);
    float* h3 = (float*)alloc((size_t)NNODES * NCLS * 4);

    const size_t cpad = ((size_t)NNODES * 4 + 255) & ~(size_t)255;
    hipMemsetAsync(cnt, 0, cpad + (size_t)NNODES * 4, stream);   // cnt + cur in one fill

    count_kernel<<<(NEDGES + 255) / 256, 256, 0, stream>>>(col, cnt, NEDGES);
    const int nsb = (NNODES + SCAN_BS - 1) / SCAN_BS;            // 98 blocks
    scan_part <<<nsb, SCAN_BS, 0, stream>>>(cnt, bsum, NNODES);
    scan_top  <<<1, 128, 0, stream>>>(bsum, nsb);
    scan_apply<<<nsb, SCAN_BS, 0, stream>>>(cnt, bsum, rp, dinv, NNODES, NEDGES);
    fill_kernel<<<(NEDGES + 255) / 256, 256, 0, stream>>>(row, col, rp, cur, csrw, dinv, NEDGES);

    cast_wt2<<<(HDIM * KP1 + HDIM * HDIM + 255) / 256, 256, 0, stream>>>(W1, W2, w1t, w2t);

    gemm1_fused<<<MPAD / 64, 256, 0, stream>>>(x, w1t, h_bf);
    agg_kernel<<<(NNODES + 3) / 4, 256, 0, stream>>>((const ushort4*)h_bf, (ushort4*)a_bf,
                                                     dinv, rp, csrw, b1, NNODES);
    gemm2_lds<<<MPAD / 64, 256, 0, stream>>>(a_bf, w2t, h_bf);
    agg2_mm3_kernel<<<(NNODES + 3) / 4, 256, 0, stream>>>((const ushort4*)h_bf, h3,
                                                          dinv, rp, csrw, b2, W3, NNODES);
    final_kernel<<<(NNODES + 255) / 256, 256, 0, stream>>>(h3, dinv, rp, csrw, b3, out, NNODES);
}